// Round 3
// baseline (419.448 us; speedup 1.0000x reference)
//
#include <hip/hip_runtime.h>
#include <hip/hip_cooperative_groups.h>
namespace cg = cooperative_groups;

// AUAvULoss fused single-pass cooperative kernel.
// probs[N,8], y[N,8] one-hot, weights[N,8] -> out[0]=avu_loss, out[1]=CE.
//
// Phase 1: 2 lanes per sample (lane parity = channel half) so all global
//          f4 loads are lane-contiguous (full coalescing). Pair combine via
//          __shfl_xor(1). Keep (unc, signed conf) for 4 samples in REGISTERS.
//          Per-block partials for focal/ce/umin/umax.
// grid.sync
// Phase 1b: every block redundantly reduces umin/umax partials (8 KB from L2);
//          block 0 reduces focal/ce in double.
// Phase 2: bucket register-held samples into x32-replicated LDS hist
//          (bin = first threshold satisfied, 21 = none); block-reduce replicas;
//          atomicAdd into x16-replicated global hist (chains <= 64).
// grid.sync
// Phase 3: block 0 reduces replicas, prefix/suffix sums -> avu[21] -> AUC -> out.
//
// Fallback (coop launch failure / N too large): round-2 proven 4-kernel path.

constexpr int C     = 8;
constexpr int NTH   = 21;
constexpr int NB    = 22;          // 0..20 first-threshold bins; 21 = none
constexpr int NBLK  = 1024;
constexpr int BS    = 256;
constexpr int TOT   = NBLK * BS;   // f4-loads per grid-iteration
constexpr int GITER = 8;           // ceil(2*1e6 / TOT)
constexpr int KMAX  = GITER / 2;   // samples kept per thread
constexpr int NREP  = 32;          // LDS hist replicas
constexpr int RSTR  = 89;          // replica stride (gcd(89%32,32)=1 -> distinct banks)
constexpr int GREP  = 16;          // global hist replicas
constexpr float LOG_FEPS = -18.420680743952367f;  // logf(1e-8f)

struct WS {
  float f_part[NBLK], c_part[NBLK], mn_part[NBLK], mx_part[NBLK];
  float ghist[GREP][4 * NB];
};

__global__ __launch_bounds__(BS, 4) void fused_k(
    const float4* __restrict__ p4, const float4* __restrict__ y4,
    const float4* __restrict__ w4, const float* __restrict__ yraw,
    WS* __restrict__ ws, float* __restrict__ out, int N) {
  cg::grid_group grid = cg::this_grid();
  const int tid = threadIdx.x;
  const int T   = blockIdx.x * BS + tid;
  const int q   = tid & 1;

  __shared__ float h[NREP * RSTR];
  __shared__ float r0[4], r1[4], r2[4], r3[4];
  __shared__ double df[4], dc[4];
  __shared__ int   sh_l0;
  __shared__ float sh_umin, sh_umax, sh_f, sh_c;
  __shared__ float hist[4 * NB];

  if (blockIdx.x == 0) {
    for (int i = tid; i < GREP * 4 * NB; i += BS) ((float*)ws->ghist)[i] = 0.f;
  }
  if (tid == 0) {
    float b = yraw[0]; int bi = 0;
#pragma unroll
    for (int j = 1; j < C; ++j) { if (yraw[j] > b) { b = yraw[j]; bi = j; } }
    sh_l0 = bi;
  }
  __syncthreads();
  const int l0 = sh_l0;

  float fsum = 0.f, csum = 0.f;
  float umin = __uint_as_float(0x7F800000u), umax = 0.f;
  float ku[KMAX], kc[KMAX];
#pragma unroll
  for (int s = 0; s < KMAX; ++s) { ku[s] = 0.f; kc[s] = 0.f; }

  const int twoN = 2 * N;
#pragma unroll
  for (int kk = 0; kk < KMAX; ++kk) {
#pragma unroll
    for (int half = 0; half < 2; ++half) {
      const int k   = 2 * kk + half;
      const int idx = k * TOT + T;
      const bool valid = idx < twoN;
      float4 pv = valid ? p4[idx] : make_float4(1.f, 1.f, 1.f, 1.f);
      float4 yv = valid ? y4[idx] : make_float4(0.f, 0.f, 0.f, 0.f);
      float4 wv = valid ? w4[idx] : make_float4(0.f, 0.f, 0.f, 0.f);
      float P[4] = {pv.x, pv.y, pv.z, pv.w};
      float Y[4] = {yv.x, yv.y, yv.z, yv.w};
      float W[4] = {wv.x, wv.y, wv.z, wv.w};
      float up = 0.f, cep = 0.f, fop = 0.f;
      float cmax = P[0]; int pid = 0;
#pragma unroll
      for (int j = 0; j < 4; ++j) {
        if (j > 0 && P[j] > cmax) { cmax = P[j]; pid = j; }  // first-occurrence
        float le = __logf(fmaxf(P[j], 1e-10f));              // entropy log, EPS=1e-10
        up -= P[j] * le;
        float lf = fmaxf(le, LOG_FEPS);                      // = log(max(p,1e-8))
        float t = Y[j] * lf;
        cep -= t; fop -= t * W[j];
      }
      pid += 4 * q;
      fsum += fop; csum += cep;            // each lane adds its own half
      float unc = up + __shfl_xor(up, 1);
      float oc  = __shfl_xor(cmax, 1);
      int   op  = __shfl_xor(pid, 1);
      float lo_c = q ? oc : cmax;  int lo_p = q ? op : pid;
      float hi_c = q ? cmax : oc;  int hi_p = q ? pid : op;
      float conf = (hi_c > lo_c) ? hi_c : lo_c;   // ties -> low half (first occ.)
      int   pred = (hi_c > lo_c) ? hi_p : lo_p;
      if (valid) {
        umin = fminf(umin, unc); umax = fmaxf(umax, unc);
        if (half == q) { ku[kk] = unc; kc[kk] = (pred == l0) ? conf : -conf; }
      }
    }
  }
  {  // block reduce -> per-block partials
    float v0 = fsum, v1 = csum, v2 = umin, v3 = umax;
#pragma unroll
    for (int o = 32; o > 0; o >>= 1) {
      v0 += __shfl_down(v0, o); v1 += __shfl_down(v1, o);
      v2 = fminf(v2, __shfl_down(v2, o)); v3 = fmaxf(v3, __shfl_down(v3, o));
    }
    int lane = tid & 63, wid = tid >> 6;
    if (lane == 0) { r0[wid] = v0; r1[wid] = v1; r2[wid] = v2; r3[wid] = v3; }
    __syncthreads();
    if (tid == 0) {
      ws->f_part[blockIdx.x]  = r0[0] + r0[1] + r0[2] + r0[3];
      ws->c_part[blockIdx.x]  = r1[0] + r1[1] + r1[2] + r1[3];
      ws->mn_part[blockIdx.x] = fminf(fminf(r2[0], r2[1]), fminf(r2[2], r2[3]));
      ws->mx_part[blockIdx.x] = fmaxf(fmaxf(r3[0], r3[1]), fmaxf(r3[2], r3[3]));
    }
  }
  __threadfence();
  grid.sync();
  __threadfence();

  {  // redundant umin/umax reduce; block 0 also focal/ce in double
    float mn = __uint_as_float(0x7F800000u), mx = 0.f;
#pragma unroll
    for (int j = 0; j < NBLK / BS; ++j) {
      int i = tid + j * BS;
      mn = fminf(mn, ws->mn_part[i]); mx = fmaxf(mx, ws->mx_part[i]);
    }
#pragma unroll
    for (int o = 32; o > 0; o >>= 1) {
      mn = fminf(mn, __shfl_down(mn, o)); mx = fmaxf(mx, __shfl_down(mx, o));
    }
    int lane = tid & 63, wid = tid >> 6;
    if (lane == 0) { r2[wid] = mn; r3[wid] = mx; }
    __syncthreads();
    if (tid == 0) {
      sh_umin = fminf(fminf(r2[0], r2[1]), fminf(r2[2], r2[3]));
      sh_umax = fmaxf(fmaxf(r3[0], r3[1]), fmaxf(r3[2], r3[3]));
    }
    if (blockIdx.x == 0) {
      double f = 0.0, c = 0.0;
      for (int i = tid; i < NBLK; i += BS) { f += (double)ws->f_part[i]; c += (double)ws->c_part[i]; }
#pragma unroll
      for (int o = 32; o > 0; o >>= 1) { f += __shfl_down(f, o); c += __shfl_down(c, o); }
      if (lane == 0) { df[wid] = f; dc[wid] = c; }
      __syncthreads();
      if (tid == 0) { sh_f = (float)(df[0] + df[1] + df[2] + df[3]);
                      sh_c = (float)(dc[0] + dc[1] + dc[2] + dc[3]); }
    }
    __syncthreads();
  }

  // Phase 2: histogram register-held samples
  for (int i = tid; i < NREP * RSTR; i += BS) h[i] = 0.f;
  __syncthreads();
  const float um = sh_umin, scale = sh_umax - um;
  float* hb = &h[(tid & (NREP - 1)) * RSTR];
#pragma unroll
  for (int s = 0; s < KMAX; ++s) {
    float cval = kc[s];
    if (cval != 0.f) {               // conf >= 1/8, so 0 marks invalid
      float unc = ku[s];
      float tu = tanhf(unc);
      int t0 = NB - 1;
      for (int t = 0; t < NTH; ++t) {
        float thr = um + ((float)t * 0.05f) * scale;  // same expr as reference
        if (unc <= thr) { t0 = t; break; }
      }
      bool corr = cval > 0.f;
      float conf = fabsf(cval);
      float base = corr ? conf : (1.f - conf);
      int row = corr ? 0 : 2;
      atomicAdd(&hb[row * NB + t0],       base * (1.f - tu));
      atomicAdd(&hb[(row + 1) * NB + t0], base * tu);
    }
  }
  __syncthreads();
  if (tid < 4 * NB) {
    float s = 0.f;
#pragma unroll
    for (int r = 0; r < NREP; ++r) s += h[r * RSTR + tid];
    atomicAdd(&ws->ghist[blockIdx.x & (GREP - 1)][tid], s);
  }
  __threadfence();
  grid.sync();
  __threadfence();

  if (blockIdx.x == 0) {
    if (tid < 4 * NB) {
      float s = 0.f;
#pragma unroll
      for (int r = 0; r < GREP; ++r) s += ws->ghist[r][tid];
      hist[tid] = s;
    }
    __syncthreads();
    if (tid == 0) {
      const float *hac = &hist[0], *hau = &hist[NB], *hic = &hist[2 * NB], *hiu = &hist[3 * NB];
      float tot_au = 0.f, tot_iu = 0.f;
      for (int s = 0; s < NB; ++s) { tot_au += hau[s]; tot_iu += hiu[s]; }
      float pac = 0.f, pau = 0.f, pic = 0.f, piu = 0.f, auc = 0.f, prev = 0.f;
      for (int t = 0; t < NTH; ++t) {
        pac += hac[t]; pau += hau[t]; pic += hic[t]; piu += hiu[t];
        float n_ac = pac, n_au = tot_au - pau, n_ic = pic, n_iu = tot_iu - piu;
        float avu = (n_ac + n_iu) / (n_ac + n_au + n_ic + n_iu + 1e-10f);
        if (t > 0) auc += 0.5f * (avu + prev) * 0.05f;
        prev = avu;
      }
      out[0] = -logf(auc + 1e-10f) + sh_f / (float)N;  // BETA = 1
      out[1] = sh_c / (float)N;
    }
  }
}

// ------------------------- fallback (round-2 proven path) -------------------------
constexpr int NBLK1 = 2048, BS1 = 256, NBLK2 = 512, BS2 = 512;

struct Accum {
  int   l0;
  float umin, umax, fsum, csum;
  float f_part[NBLK1], c_part[NBLK1], mn_part[NBLK1], mx_part[NBLK1];
};

__global__ __launch_bounds__(BS1) void pass1_k(const float4* __restrict__ p4,
                                               const float4* __restrict__ y4,
                                               const float4* __restrict__ w4,
                                               const float*  __restrict__ yraw,
                                               Accum* __restrict__ acc,
                                               float2* __restrict__ stash, int N) {
  __shared__ int sh_l0;
  if (threadIdx.x == 0) {
    float best = yraw[0]; int bi = 0;
#pragma unroll
    for (int j = 1; j < C; ++j) { if (yraw[j] > best) { best = yraw[j]; bi = j; } }
    sh_l0 = bi;
    if (blockIdx.x == 0) acc->l0 = bi;
  }
  __syncthreads();
  const int l0 = sh_l0;
  float fsum = 0.f, csum = 0.f;
  float umin = __uint_as_float(0x7F800000u), umax = 0.f;
  int stride = gridDim.x * blockDim.x;
  for (int i = blockIdx.x * blockDim.x + threadIdx.x; i < N; i += stride) {
    float4 a = p4[2 * i], b = p4[2 * i + 1];
    float4 ya = y4[2 * i], yb = y4[2 * i + 1];
    float4 wa = w4[2 * i], wb = w4[2 * i + 1];
    float p[8]  = {a.x, a.y, a.z, a.w, b.x, b.y, b.z, b.w};
    float yy[8] = {ya.x, ya.y, ya.z, ya.w, yb.x, yb.y, yb.z, yb.w};
    float ww[8] = {wa.x, wa.y, wa.z, wa.w, wb.x, wb.y, wb.z, wb.w};
    float unc = 0.f, ce = 0.f, fo = 0.f;
    float conf = p[0]; int pred = 0;
#pragma unroll
    for (int j = 0; j < 8; ++j) {
      if (p[j] > conf) { conf = p[j]; pred = j; }
      float le = __logf(fmaxf(p[j], 1e-10f));
      unc -= p[j] * le;
      float lf = fmaxf(le, LOG_FEPS);
      float t = yy[j] * lf;
      ce -= t; fo -= t * ww[j];
    }
    stash[i] = make_float2(unc, (pred == l0) ? conf : -conf);
    fsum += fo; csum += ce;
    umin = fminf(umin, unc); umax = fmaxf(umax, unc);
  }
  float v0 = fsum, v1 = csum, v2 = umin, v3 = umax;
#pragma unroll
  for (int o = 32; o > 0; o >>= 1) {
    v0 += __shfl_down(v0, o); v1 += __shfl_down(v1, o);
    v2 = fminf(v2, __shfl_down(v2, o)); v3 = fmaxf(v3, __shfl_down(v3, o));
  }
  __shared__ float r0[4], r1[4], r2[4], r3[4];
  int lane = threadIdx.x & 63, wid = threadIdx.x >> 6;
  if (lane == 0) { r0[wid] = v0; r1[wid] = v1; r2[wid] = v2; r3[wid] = v3; }
  __syncthreads();
  if (threadIdx.x == 0) {
    acc->f_part[blockIdx.x]  = r0[0] + r0[1] + r0[2] + r0[3];
    acc->c_part[blockIdx.x]  = r1[0] + r1[1] + r1[2] + r1[3];
    acc->mn_part[blockIdx.x] = fminf(fminf(r2[0], r2[1]), fminf(r2[2], r2[3]));
    acc->mx_part[blockIdx.x] = fmaxf(fmaxf(r3[0], r3[1]), fmaxf(r3[2], r3[3]));
  }
}

__global__ __launch_bounds__(256) void mid_k(Accum* __restrict__ acc) {
  double f = 0.0, c = 0.0;
  float mn = __uint_as_float(0x7F800000u), mx = 0.f;
  for (int i = threadIdx.x; i < NBLK1; i += 256) {
    f += (double)acc->f_part[i]; c += (double)acc->c_part[i];
    mn = fminf(mn, acc->mn_part[i]); mx = fmaxf(mx, acc->mx_part[i]);
  }
  __shared__ double sf[4], sc[4];
  __shared__ float smn[4], smx[4];
  int lane = threadIdx.x & 63, wid = threadIdx.x >> 6;
#pragma unroll
  for (int o = 32; o > 0; o >>= 1) {
    f += __shfl_down(f, o); c += __shfl_down(c, o);
    mn = fminf(mn, __shfl_down(mn, o)); mx = fmaxf(mx, __shfl_down(mx, o));
  }
  if (lane == 0) { sf[wid] = f; sc[wid] = c; smn[wid] = mn; smx[wid] = mx; }
  __syncthreads();
  if (threadIdx.x == 0) {
    acc->fsum = (float)(sf[0] + sf[1] + sf[2] + sf[3]);
    acc->csum = (float)(sc[0] + sc[1] + sc[2] + sc[3]);
    acc->umin = fminf(fminf(smn[0], smn[1]), fminf(smn[2], smn[3]));
    acc->umax = fmaxf(fmaxf(smx[0], smx[1]), fmaxf(smx[2], smx[3]));
  }
}

__global__ __launch_bounds__(BS2) void pass2_k(const float2* __restrict__ stash,
                                               const Accum* __restrict__ acc,
                                               float* __restrict__ partial2, int N) {
  __shared__ float h[NREP * RSTR];
  for (int k = threadIdx.x; k < NREP * RSTR; k += BS2) h[k] = 0.f;
  __syncthreads();
  const float umin = acc->umin;
  const float scale = acc->umax - umin;
  float* hb = &h[(threadIdx.x & (NREP - 1)) * RSTR];
  int stride = gridDim.x * blockDim.x;
  for (int i = blockIdx.x * blockDim.x + threadIdx.x; i < N; i += stride) {
    float2 s = stash[i];
    float unc = s.x, cval = s.y;
    float tu = tanhf(unc);
    int t0 = NB - 1;
    for (int t = 0; t < NTH; ++t) {
      float thr = umin + ((float)t * 0.05f) * scale;
      if (unc <= thr) { t0 = t; break; }
    }
    bool corr = cval > 0.f;
    float conf = fabsf(cval);
    float base = corr ? conf : (1.f - conf);
    int row = corr ? 0 : 2;
    atomicAdd(&hb[row * NB + t0],       base * (1.f - tu));
    atomicAdd(&hb[(row + 1) * NB + t0], base * tu);
  }
  __syncthreads();
  for (int idx = threadIdx.x; idx < 4 * NB; idx += BS2) {
    float s = 0.f;
#pragma unroll
    for (int r = 0; r < NREP; ++r) s += h[r * RSTR + idx];
    partial2[idx * NBLK2 + blockIdx.x] = s;
  }
}

__global__ __launch_bounds__(1024) void final_k(const float* __restrict__ partial2,
                                                const Accum* __restrict__ acc,
                                                float* __restrict__ out, int N) {
  __shared__ float hist[4 * NB];
  int lane = threadIdx.x & 63, wid = threadIdx.x >> 6;
  for (int cidx = wid; cidx < 4 * NB; cidx += 16) {
    float s = 0.f;
    for (int k = lane; k < NBLK2; k += 64) s += partial2[cidx * NBLK2 + k];
#pragma unroll
    for (int o = 32; o > 0; o >>= 1) s += __shfl_down(s, o);
    if (lane == 0) hist[cidx] = s;
  }
  __syncthreads();
  if (threadIdx.x == 0) {
    const float *hac = &hist[0], *hau = &hist[NB], *hic = &hist[2 * NB], *hiu = &hist[3 * NB];
    float tot_au = 0.f, tot_iu = 0.f;
    for (int s = 0; s < NB; ++s) { tot_au += hau[s]; tot_iu += hiu[s]; }
    float pac = 0.f, pau = 0.f, pic = 0.f, piu = 0.f, auc = 0.f, prev = 0.f;
    for (int t = 0; t < NTH; ++t) {
      pac += hac[t]; pau += hau[t]; pic += hic[t]; piu += hiu[t];
      float n_ac = pac, n_au = tot_au - pau, n_ic = pic, n_iu = tot_iu - piu;
      float avu = (n_ac + n_iu) / (n_ac + n_au + n_ic + n_iu + 1e-10f);
      if (t > 0) auc += 0.5f * (avu + prev) * 0.05f;
      prev = avu;
    }
    out[0] = -logf(auc + 1e-10f) + acc->fsum / (float)N;
    out[1] = acc->csum / (float)N;
  }
}

extern "C" void kernel_launch(void* const* d_in, const int* in_sizes, int n_in,
                              void* d_out, int out_size, void* d_ws, size_t ws_size,
                              hipStream_t stream) {
  const float* probs = (const float*)d_in[0];
  const float* y     = (const float*)d_in[1];
  const float* w     = (const float*)d_in[2];
  float* out = (float*)d_out;
  int N = in_sizes[0] / C;

  bool coop_ok = (2 * N <= GITER * TOT) && (ws_size >= sizeof(WS));
  if (coop_ok) {
    WS* ws = (WS*)d_ws;
    const float4* p4 = (const float4*)probs;
    const float4* y4 = (const float4*)y;
    const float4* w4 = (const float4*)w;
    void* args[] = {(void*)&p4, (void*)&y4, (void*)&w4, (void*)&y,
                    (void*)&ws, (void*)&out, (void*)&N};
    hipError_t e = hipLaunchCooperativeKernel((const void*)fused_k, dim3(NBLK),
                                              dim3(BS), args, 0, stream);
    if (e == hipSuccess) return;
  }
  // Fallback: proven 4-kernel pipeline.
  Accum* acc = (Accum*)d_ws;
  size_t off_p2 = (sizeof(Accum) + 255) & ~(size_t)255;
  size_t off_st = (off_p2 + (size_t)(4 * NB) * NBLK2 * sizeof(float) + 255) & ~(size_t)255;
  float*  partial2 = (float*)((char*)d_ws + off_p2);
  float2* stash    = (float2*)((char*)d_ws + off_st);
  pass1_k<<<NBLK1, BS1, 0, stream>>>((const float4*)probs, (const float4*)y,
                                     (const float4*)w, y, acc, stash, N);
  mid_k<<<1, 256, 0, stream>>>(acc);
  pass2_k<<<NBLK2, BS2, 0, stream>>>(stash, acc, partial2, N);
  final_k<<<1, 1024, 0, stream>>>(partial2, acc, out, N);
}

// Round 4
// 58.359 us; speedup vs baseline: 7.1873x; 7.1873x over previous
//
#include <hip/hip_runtime.h>

// AUAvULoss: probs[N,8], y[N,8] one-hot, weights[N,8] -> (avu_loss, CE_loss)
//
// 3-kernel pipeline (kernel boundaries = free device-wide sync; NO grid.sync /
// __threadfence on MI355X — cross-XCD fences compile to per-wave L2 writebacks,
// measured 426us disaster in round 3).
//
// pass1_k : 2 LANES PER SAMPLE (lane parity = channel half) so every float4
//           load is lane-contiguous (full coalescing). Pair-combine unc/conf/
//           pred via __shfl_xor(.,1) (verified bit-exact in round 3).
//           Stash (unc, correct?conf:-conf) to ws; per-block partials for
//           focal/ce/umin/umax. No global atomics.
// pass2_k : each block redundantly reduces the 2048 min/max partials (16 KB
//           from L2) -- replaces the former mid_k launch. Then buckets stash
//           samples by first-threshold index into x32-replicated LDS hist,
//           flushes as non-atomic per-block partial writes [88][NBLK2].
// final_k : reduces focal/ce partials (double) + hist partials, prefix/suffix
//           sums -> avu[21] -> trapezoid AUC -> out[0]=avu_loss, out[1]=CE.
//
// Fallback if ws too small for stash: pass2f_k re-reads probs (exact same math).

constexpr int C     = 8;
constexpr int NTH   = 21;
constexpr int NB    = 22;     // 0..20 = first threshold satisfied; 21 = none
constexpr int NBLK1 = 2048;
constexpr int BS1   = 256;
constexpr int NBLK2 = 512;
constexpr int BS2   = 512;
constexpr int NREP  = 32;     // LDS hist replicas
constexpr int RSTR  = 89;     // replica stride (odd -> distinct banks)
constexpr float LOG_FEPS = -18.420680743952367f;  // logf(1e-8f)

struct Accum {
  int   l0;
  float f_part[NBLK1], c_part[NBLK1], mn_part[NBLK1], mx_part[NBLK1];
};

template <bool STASH>
__global__ __launch_bounds__(BS1) void pass1_k(const float4* __restrict__ p4,
                                               const float4* __restrict__ y4,
                                               const float4* __restrict__ w4,
                                               const float*  __restrict__ yraw,
                                               Accum* __restrict__ acc,
                                               float2* __restrict__ stash, int N) {
  __shared__ int sh_l0;
  if (threadIdx.x == 0) {
    float best = yraw[0]; int bi = 0;
#pragma unroll
    for (int j = 1; j < C; ++j) { if (yraw[j] > best) { best = yraw[j]; bi = j; } }
    sh_l0 = bi;
    if (blockIdx.x == 0) acc->l0 = bi;
  }
  __syncthreads();
  const int l0 = sh_l0;
  const int q  = threadIdx.x & 1;          // channel half (0: ch0-3, 1: ch4-7)
  const int T  = blockIdx.x * BS1 + threadIdx.x;
  const int S  = NBLK1 * BS1;
  const int twoN = 2 * N;                  // total float4s per array (even)

  float fsum = 0.f, csum = 0.f;
  float umin = __uint_as_float(0x7F800000u), umax = 0.f;

  for (int idx = T; idx < twoN; idx += S) {
    float4 pv = p4[idx];
    float4 yv = y4[idx];
    float4 wv = w4[idx];
    float P[4] = {pv.x, pv.y, pv.z, pv.w};
    float Y[4] = {yv.x, yv.y, yv.z, yv.w};
    float W[4] = {wv.x, wv.y, wv.z, wv.w};
    float up = 0.f, cep = 0.f, fop = 0.f;
    float cmax = P[0]; int pid = 0;
#pragma unroll
    for (int j = 0; j < 4; ++j) {
      if (j > 0 && P[j] > cmax) { cmax = P[j]; pid = j; }  // first-occurrence
      float le = __logf(fmaxf(P[j], 1e-10f));              // entropy log (EPS=1e-10)
      up -= P[j] * le;
      float lf = fmaxf(le, LOG_FEPS);                      // = log(max(p,1e-8))
      float t  = Y[j] * lf;
      cep -= t; fop -= t * W[j];
    }
    pid += 4 * q;
    fsum += fop; csum += cep;              // each lane adds its own half
    float unc = up + __shfl_xor(up, 1);
    float oc  = __shfl_xor(cmax, 1);
    int   op  = __shfl_xor(pid, 1);
    float lo_c = q ? oc : cmax;  int lo_p = q ? op : pid;
    float hi_c = q ? cmax : oc;  int hi_p = q ? pid : op;
    float conf = (hi_c > lo_c) ? hi_c : lo_c;   // ties -> low half (first occ.)
    int   pred = (hi_c > lo_c) ? hi_p : lo_p;
    umin = fminf(umin, unc); umax = fmaxf(umax, unc);
    if (STASH && q == 0)                   // even lanes: contiguous float2 runs
      stash[idx >> 1] = make_float2(unc, (pred == l0) ? conf : -conf);
  }

  float v0 = fsum, v1 = csum, v2 = umin, v3 = umax;
#pragma unroll
  for (int o = 32; o > 0; o >>= 1) {
    v0 += __shfl_down(v0, o); v1 += __shfl_down(v1, o);
    v2 = fminf(v2, __shfl_down(v2, o)); v3 = fmaxf(v3, __shfl_down(v3, o));
  }
  __shared__ float r0[4], r1[4], r2[4], r3[4];
  int lane = threadIdx.x & 63, wid = threadIdx.x >> 6;
  if (lane == 0) { r0[wid] = v0; r1[wid] = v1; r2[wid] = v2; r3[wid] = v3; }
  __syncthreads();
  if (threadIdx.x == 0) {
    acc->f_part[blockIdx.x]  = r0[0] + r0[1] + r0[2] + r0[3];
    acc->c_part[blockIdx.x]  = r1[0] + r1[1] + r1[2] + r1[3];
    acc->mn_part[blockIdx.x] = fminf(fminf(r2[0], r2[1]), fminf(r2[2], r2[3]));
    acc->mx_part[blockIdx.x] = fmaxf(fmaxf(r3[0], r3[1]), fmaxf(r3[2], r3[3]));
  }
}

// Redundant per-block umin/umax reduction (replaces mid_k launch).
__device__ __forceinline__ void reduce_minmax(const Accum* __restrict__ acc,
                                              float& out_umin, float& out_scale) {
  __shared__ float rmn[BS2 / 64], rmx[BS2 / 64];
  __shared__ float sh_umin, sh_umax;
  float mn = __uint_as_float(0x7F800000u), mx = 0.f;
  for (int i = threadIdx.x; i < NBLK1; i += BS2) {
    mn = fminf(mn, acc->mn_part[i]);
    mx = fmaxf(mx, acc->mx_part[i]);
  }
#pragma unroll
  for (int o = 32; o > 0; o >>= 1) {
    mn = fminf(mn, __shfl_down(mn, o));
    mx = fmaxf(mx, __shfl_down(mx, o));
  }
  int lane = threadIdx.x & 63, wid = threadIdx.x >> 6;
  if (lane == 0) { rmn[wid] = mn; rmx[wid] = mx; }
  __syncthreads();
  if (threadIdx.x == 0) {
    float a = rmn[0], b = rmx[0];
#pragma unroll
    for (int wv = 1; wv < BS2 / 64; ++wv) { a = fminf(a, rmn[wv]); b = fmaxf(b, rmx[wv]); }
    sh_umin = a; sh_umax = b;
  }
  __syncthreads();
  out_umin = sh_umin; out_scale = sh_umax - sh_umin;
}

__device__ __forceinline__ void hist_update(float* hb, float unc, float cval,
                                            float umin, float scale) {
  float tu = tanhf(unc);
  int t0 = NB - 1;
  for (int t = 0; t < NTH; ++t) {
    float thr = umin + ((float)t * 0.05f) * scale;  // same expr as reference
    if (unc <= thr) { t0 = t; break; }
  }
  bool  corr = cval > 0.f;
  float conf = fabsf(cval);
  float base = corr ? conf : (1.f - conf);
  int   row  = corr ? 0 : 2;
  atomicAdd(&hb[row * NB + t0],       base * (1.f - tu));
  atomicAdd(&hb[(row + 1) * NB + t0], base * tu);
}

__global__ __launch_bounds__(BS2) void pass2_k(const float2* __restrict__ stash,
                                               const Accum* __restrict__ acc,
                                               float* __restrict__ partial2, int N) {
  __shared__ float h[NREP * RSTR];
  for (int k = threadIdx.x; k < NREP * RSTR; k += BS2) h[k] = 0.f;
  float umin, scale;
  reduce_minmax(acc, umin, scale);   // contains __syncthreads (covers h init)
  float* hb = &h[(threadIdx.x & (NREP - 1)) * RSTR];
  int stride = gridDim.x * blockDim.x;
  for (int i = blockIdx.x * blockDim.x + threadIdx.x; i < N; i += stride) {
    float2 s = stash[i];
    hist_update(hb, s.x, s.y, umin, scale);
  }
  __syncthreads();
  for (int idx = threadIdx.x; idx < 4 * NB; idx += BS2) {
    float s = 0.f;
#pragma unroll
    for (int r = 0; r < NREP; ++r) s += h[r * RSTR + idx];
    partial2[idx * NBLK2 + blockIdx.x] = s;
  }
}

// Fallback: no stash space -> re-read probs, recompute conf/pred/unc.
__global__ __launch_bounds__(BS2) void pass2f_k(const float4* __restrict__ p4,
                                                const Accum* __restrict__ acc,
                                                float* __restrict__ partial2, int N) {
  __shared__ float h[NREP * RSTR];
  for (int k = threadIdx.x; k < NREP * RSTR; k += BS2) h[k] = 0.f;
  float umin, scale;
  reduce_minmax(acc, umin, scale);
  const int l0 = acc->l0;
  float* hb = &h[(threadIdx.x & (NREP - 1)) * RSTR];
  int stride = gridDim.x * blockDim.x;
  for (int i = blockIdx.x * blockDim.x + threadIdx.x; i < N; i += stride) {
    float4 a = p4[2 * i], b = p4[2 * i + 1];
    float p[8] = {a.x, a.y, a.z, a.w, b.x, b.y, b.z, b.w};
    float conf = p[0]; int pred = 0;
    float unc = 0.f;
#pragma unroll
    for (int j = 0; j < 8; ++j) {
      if (p[j] > conf) { conf = p[j]; pred = j; }
      unc -= p[j] * __logf(fmaxf(p[j], 1e-10f));
    }
    hist_update(hb, unc, (pred == l0) ? conf : -conf, umin, scale);
  }
  __syncthreads();
  for (int idx = threadIdx.x; idx < 4 * NB; idx += BS2) {
    float s = 0.f;
#pragma unroll
    for (int r = 0; r < NREP; ++r) s += h[r * RSTR + idx];
    partial2[idx * NBLK2 + blockIdx.x] = s;
  }
}

__global__ __launch_bounds__(1024) void final_k(const float* __restrict__ partial2,
                                                const Accum* __restrict__ acc,
                                                float* __restrict__ out, int N) {
  __shared__ float hist[4 * NB];
  __shared__ double df[16], dc[16];
  __shared__ float sh_f, sh_c;
  int lane = threadIdx.x & 63, wid = threadIdx.x >> 6;  // 16 waves

  // focal/ce reduce (double) over NBLK1 partials
  double f = 0.0, c = 0.0;
  for (int i = threadIdx.x; i < NBLK1; i += 1024) {
    f += (double)acc->f_part[i]; c += (double)acc->c_part[i];
  }
#pragma unroll
  for (int o = 32; o > 0; o >>= 1) { f += __shfl_down(f, o); c += __shfl_down(c, o); }
  if (lane == 0) { df[wid] = f; dc[wid] = c; }

  // histogram reduce: one wave per bin row
  for (int cidx = wid; cidx < 4 * NB; cidx += 16) {
    float s = 0.f;
    for (int k = lane; k < NBLK2; k += 64) s += partial2[cidx * NBLK2 + k];
#pragma unroll
    for (int o = 32; o > 0; o >>= 1) s += __shfl_down(s, o);
    if (lane == 0) hist[cidx] = s;
  }
  __syncthreads();
  if (threadIdx.x == 0) {
    double ft = 0.0, ct = 0.0;
#pragma unroll
    for (int wv = 0; wv < 16; ++wv) { ft += df[wv]; ct += dc[wv]; }
    sh_f = (float)ft; sh_c = (float)ct;

    const float *hac = &hist[0], *hau = &hist[NB], *hic = &hist[2 * NB], *hiu = &hist[3 * NB];
    float tot_au = 0.f, tot_iu = 0.f;
    for (int s = 0; s < NB; ++s) { tot_au += hau[s]; tot_iu += hiu[s]; }
    float pac = 0.f, pau = 0.f, pic = 0.f, piu = 0.f, auc = 0.f, prev = 0.f;
    for (int t = 0; t < NTH; ++t) {
      pac += hac[t]; pau += hau[t]; pic += hic[t]; piu += hiu[t];
      float n_ac = pac, n_au = tot_au - pau, n_ic = pic, n_iu = tot_iu - piu;
      float avu = (n_ac + n_iu) / (n_ac + n_au + n_ic + n_iu + 1e-10f);
      if (t > 0) auc += 0.5f * (avu + prev) * 0.05f;
      prev = avu;
    }
    out[0] = -logf(auc + 1e-10f) + sh_f / (float)N;  // BETA = 1
    out[1] = sh_c / (float)N;
  }
}

extern "C" void kernel_launch(void* const* d_in, const int* in_sizes, int n_in,
                              void* d_out, int out_size, void* d_ws, size_t ws_size,
                              hipStream_t stream) {
  const float* probs = (const float*)d_in[0];
  const float* y     = (const float*)d_in[1];
  const float* w     = (const float*)d_in[2];
  float* out = (float*)d_out;
  int N = in_sizes[0] / C;

  Accum* acc = (Accum*)d_ws;
  size_t off_p2 = (sizeof(Accum) + 255) & ~(size_t)255;
  size_t off_st = (off_p2 + (size_t)(4 * NB) * NBLK2 * sizeof(float) + 255) & ~(size_t)255;
  size_t need   = off_st + (size_t)N * sizeof(float2);
  float*  partial2 = (float*)((char*)d_ws + off_p2);
  float2* stash    = (float2*)((char*)d_ws + off_st);

  if (ws_size >= need) {
    pass1_k<true><<<NBLK1, BS1, 0, stream>>>((const float4*)probs, (const float4*)y,
                                             (const float4*)w, y, acc, stash, N);
    pass2_k<<<NBLK2, BS2, 0, stream>>>(stash, acc, partial2, N);
  } else {
    pass1_k<false><<<NBLK1, BS1, 0, stream>>>((const float4*)probs, (const float4*)y,
                                              (const float4*)w, y, acc, nullptr, N);
    pass2f_k<<<NBLK2, BS2, 0, stream>>>((const float4*)probs, acc, partial2, N);
  }
  final_k<<<1, 1024, 0, stream>>>(partial2, acc, out, N);
}

// Round 5
// 58.119 us; speedup vs baseline: 7.2170x; 1.0041x over previous
//
#include <hip/hip_runtime.h>

// AUAvULoss: probs[N,8], y[N,8] one-hot, weights[N,8] -> (avu_loss, CE_loss)
//
// 3-kernel pipeline (kernel boundaries = free device-wide sync; NO grid.sync
// on MI355X — round-3 measured 426us disaster from cross-XCD fence costs).
//
// pass1_k : THE hot kernel (reads 96 MB). R4's pair scheme (2 lanes/sample,
//           shfl_xor combine — bit-exact verified) + NEW: per-stream BATCHED
//           loads. Each wave issues 8x dwordx4 of p, then 8x of y, then 8x of
//           w (8 KB contiguous per stream per wave, 24 loads in flight) before
//           computing. Rationale: R2/R4 both plateaued at ~2.4 TB/s with
//           3 interleaved lockstep streams (round-robin every 64B per HBM
//           channel + identical alloc alignment -> row thrash). Batching gives
//           8 KB same-stream runs. Stash (unc, correct?conf:-conf); per-block
//           partials for focal/ce/umin/umax. No global atomics.
// pass2_k : redundant per-block min/max reduce (16 KB from L2), then buckets
//           stash samples by first-threshold index into x32-replicated LDS
//           hist, flushes non-atomic per-block partials [88][NBLK2].
// final_k : reduces focal/ce (double) + hist partials, prefix/suffix sums ->
//           avu[21] -> trapezoid AUC -> out[0]=avu_loss, out[1]=CE.

constexpr int C     = 8;
constexpr int NTH   = 21;
constexpr int NB    = 22;     // 0..20 = first threshold satisfied; 21 = none
constexpr int NBLK1 = 1024;
constexpr int BS1   = 256;
constexpr int KB    = 8;      // f4s per lane per stream per macro-iter
constexpr int NBLK2 = 512;
constexpr int BS2   = 512;
constexpr int NREP  = 32;     // LDS hist replicas
constexpr int RSTR  = 89;     // replica stride (odd -> distinct banks)
constexpr float LOG_FEPS = -18.420680743952367f;  // logf(1e-8f)

struct Accum {
  int   l0;
  float f_part[NBLK1], c_part[NBLK1], mn_part[NBLK1], mx_part[NBLK1];
};

template <bool STASH>
__global__ __launch_bounds__(BS1) void pass1_k(const float4* __restrict__ p4,
                                               const float4* __restrict__ y4,
                                               const float4* __restrict__ w4,
                                               const float*  __restrict__ yraw,
                                               Accum* __restrict__ acc,
                                               float2* __restrict__ stash, int N) {
  __shared__ int sh_l0;
  if (threadIdx.x == 0) {
    float best = yraw[0]; int bi = 0;
#pragma unroll
    for (int j = 1; j < C; ++j) { if (yraw[j] > best) { best = yraw[j]; bi = j; } }
    sh_l0 = bi;
    if (blockIdx.x == 0) acc->l0 = bi;
  }
  __syncthreads();
  const int l0   = sh_l0;
  const int tid  = threadIdx.x;
  const int q    = tid & 1;                       // channel half
  const int lane = tid & 63;
  const int W    = (blockIdx.x * BS1 + tid) >> 6; // global wave id
  const int twoN = 2 * N;                         // f4s per array (even)
  const int MSTR = (NBLK1 * BS1 / 64) * (64 * KB);// f4 stride per macro-iter

  float fsum = 0.f, csum = 0.f;
  float umin = __uint_as_float(0x7F800000u), umax = 0.f;

  for (int wb = W * (64 * KB); wb < twoN; wb += MSTR) {
    const int maxi = twoN - 1;
    // ---- batched loads: 8 KB per stream per wave, grouped by stream ----
    float4 pv[KB], yv[KB], wv[KB];
#pragma unroll
    for (int k = 0; k < KB; ++k) { int i = wb + k * 64 + lane; pv[k] = p4[i <= maxi ? i : maxi]; }
#pragma unroll
    for (int k = 0; k < KB; ++k) { int i = wb + k * 64 + lane; yv[k] = y4[i <= maxi ? i : maxi]; }
#pragma unroll
    for (int k = 0; k < KB; ++k) { int i = wb + k * 64 + lane; wv[k] = w4[i <= maxi ? i : maxi]; }
    // ---- compute: pair scheme (2 lanes/sample), verified bit-exact ----
#pragma unroll
    for (int k = 0; k < KB; ++k) {
      const int  idx   = wb + k * 64 + lane;
      const bool valid = idx < twoN;              // pairs never split (twoN even)
      float P[4] = {pv[k].x, pv[k].y, pv[k].z, pv[k].w};
      float Y[4] = {yv[k].x, yv[k].y, yv[k].z, yv[k].w};
      float Wt[4] = {wv[k].x, wv[k].y, wv[k].z, wv[k].w};
      float up = 0.f, cep = 0.f, fop = 0.f;
      float cmax = P[0]; int pid = 0;
#pragma unroll
      for (int j = 0; j < 4; ++j) {
        if (j > 0 && P[j] > cmax) { cmax = P[j]; pid = j; }  // first-occurrence
        float le = __logf(fmaxf(P[j], 1e-10f));              // entropy log (EPS=1e-10)
        up -= P[j] * le;
        float lf = fmaxf(le, LOG_FEPS);                      // = log(max(p,1e-8))
        float t  = Y[j] * lf;
        cep -= t; fop -= t * Wt[j];
      }
      pid += 4 * q;
      float unc = up + __shfl_xor(up, 1);
      float oc  = __shfl_xor(cmax, 1);
      int   op  = __shfl_xor(pid, 1);
      float lo_c = q ? oc : cmax;  int lo_p = q ? op : pid;
      float hi_c = q ? cmax : oc;  int hi_p = q ? pid : op;
      float conf = (hi_c > lo_c) ? hi_c : lo_c;   // ties -> low half (first occ.)
      int   pred = (hi_c > lo_c) ? hi_p : lo_p;
      if (valid) {
        fsum += fop; csum += cep;                 // each lane adds its own half
        umin = fminf(umin, unc); umax = fmaxf(umax, unc);
        if (STASH && q == 0)
          stash[idx >> 1] = make_float2(unc, (pred == l0) ? conf : -conf);
      }
    }
  }

  float v0 = fsum, v1 = csum, v2 = umin, v3 = umax;
#pragma unroll
  for (int o = 32; o > 0; o >>= 1) {
    v0 += __shfl_down(v0, o); v1 += __shfl_down(v1, o);
    v2 = fminf(v2, __shfl_down(v2, o)); v3 = fmaxf(v3, __shfl_down(v3, o));
  }
  __shared__ float r0[4], r1[4], r2[4], r3[4];
  int ln = tid & 63, wd = tid >> 6;
  if (ln == 0) { r0[wd] = v0; r1[wd] = v1; r2[wd] = v2; r3[wd] = v3; }
  __syncthreads();
  if (tid == 0) {
    acc->f_part[blockIdx.x]  = r0[0] + r0[1] + r0[2] + r0[3];
    acc->c_part[blockIdx.x]  = r1[0] + r1[1] + r1[2] + r1[3];
    acc->mn_part[blockIdx.x] = fminf(fminf(r2[0], r2[1]), fminf(r2[2], r2[3]));
    acc->mx_part[blockIdx.x] = fmaxf(fmaxf(r3[0], r3[1]), fmaxf(r3[2], r3[3]));
  }
}

// Redundant per-block umin/umax reduction (no extra kernel launch).
__device__ __forceinline__ void reduce_minmax(const Accum* __restrict__ acc,
                                              float& out_umin, float& out_scale) {
  __shared__ float rmn[BS2 / 64], rmx[BS2 / 64];
  __shared__ float sh_umin, sh_umax;
  float mn = __uint_as_float(0x7F800000u), mx = 0.f;
  for (int i = threadIdx.x; i < NBLK1; i += BS2) {
    mn = fminf(mn, acc->mn_part[i]);
    mx = fmaxf(mx, acc->mx_part[i]);
  }
#pragma unroll
  for (int o = 32; o > 0; o >>= 1) {
    mn = fminf(mn, __shfl_down(mn, o));
    mx = fmaxf(mx, __shfl_down(mx, o));
  }
  int lane = threadIdx.x & 63, wid = threadIdx.x >> 6;
  if (lane == 0) { rmn[wid] = mn; rmx[wid] = mx; }
  __syncthreads();
  if (threadIdx.x == 0) {
    float a = rmn[0], b = rmx[0];
#pragma unroll
    for (int wv = 1; wv < BS2 / 64; ++wv) { a = fminf(a, rmn[wv]); b = fmaxf(b, rmx[wv]); }
    sh_umin = a; sh_umax = b;
  }
  __syncthreads();
  out_umin = sh_umin; out_scale = sh_umax - sh_umin;
}

__device__ __forceinline__ void hist_update(float* hb, float unc, float cval,
                                            float umin, float scale) {
  float tu = tanhf(unc);
  int t0 = NB - 1;
  for (int t = 0; t < NTH; ++t) {
    float thr = umin + ((float)t * 0.05f) * scale;  // same expr as reference
    if (unc <= thr) { t0 = t; break; }
  }
  bool  corr = cval > 0.f;
  float conf = fabsf(cval);
  float base = corr ? conf : (1.f - conf);
  int   row  = corr ? 0 : 2;
  atomicAdd(&hb[row * NB + t0],       base * (1.f - tu));
  atomicAdd(&hb[(row + 1) * NB + t0], base * tu);
}

__global__ __launch_bounds__(BS2) void pass2_k(const float2* __restrict__ stash,
                                               const Accum* __restrict__ acc,
                                               float* __restrict__ partial2, int N) {
  __shared__ float h[NREP * RSTR];
  for (int k = threadIdx.x; k < NREP * RSTR; k += BS2) h[k] = 0.f;
  float umin, scale;
  reduce_minmax(acc, umin, scale);   // contains __syncthreads (covers h init)
  float* hb = &h[(threadIdx.x & (NREP - 1)) * RSTR];
  int stride = gridDim.x * blockDim.x;
  for (int i = blockIdx.x * blockDim.x + threadIdx.x; i < N; i += stride) {
    float2 s = stash[i];
    hist_update(hb, s.x, s.y, umin, scale);
  }
  __syncthreads();
  for (int idx = threadIdx.x; idx < 4 * NB; idx += BS2) {
    float s = 0.f;
#pragma unroll
    for (int r = 0; r < NREP; ++r) s += h[r * RSTR + idx];
    partial2[idx * NBLK2 + blockIdx.x] = s;
  }
}

// Fallback: no stash space -> re-read probs, recompute conf/pred/unc.
__global__ __launch_bounds__(BS2) void pass2f_k(const float4* __restrict__ p4,
                                                const Accum* __restrict__ acc,
                                                float* __restrict__ partial2, int N) {
  __shared__ float h[NREP * RSTR];
  for (int k = threadIdx.x; k < NREP * RSTR; k += BS2) h[k] = 0.f;
  float umin, scale;
  reduce_minmax(acc, umin, scale);
  const int l0 = acc->l0;
  float* hb = &h[(threadIdx.x & (NREP - 1)) * RSTR];
  int stride = gridDim.x * blockDim.x;
  for (int i = blockIdx.x * blockDim.x + threadIdx.x; i < N; i += stride) {
    float4 a = p4[2 * i], b = p4[2 * i + 1];
    float p[8] = {a.x, a.y, a.z, a.w, b.x, b.y, b.z, b.w};
    float conf = p[0]; int pred = 0;
    float unc = 0.f;
#pragma unroll
    for (int j = 0; j < 8; ++j) {
      if (p[j] > conf) { conf = p[j]; pred = j; }
      unc -= p[j] * __logf(fmaxf(p[j], 1e-10f));
    }
    hist_update(hb, unc, (pred == l0) ? conf : -conf, umin, scale);
  }
  __syncthreads();
  for (int idx = threadIdx.x; idx < 4 * NB; idx += BS2) {
    float s = 0.f;
#pragma unroll
    for (int r = 0; r < NREP; ++r) s += h[r * RSTR + idx];
    partial2[idx * NBLK2 + blockIdx.x] = s;
  }
}

__global__ __launch_bounds__(1024) void final_k(const float* __restrict__ partial2,
                                                const Accum* __restrict__ acc,
                                                float* __restrict__ out, int N) {
  __shared__ float hist[4 * NB];
  __shared__ double df[16], dc[16];
  __shared__ float sh_f, sh_c;
  int lane = threadIdx.x & 63, wid = threadIdx.x >> 6;  // 16 waves

  double f = 0.0, c = 0.0;
  for (int i = threadIdx.x; i < NBLK1; i += 1024) {
    f += (double)acc->f_part[i]; c += (double)acc->c_part[i];
  }
#pragma unroll
  for (int o = 32; o > 0; o >>= 1) { f += __shfl_down(f, o); c += __shfl_down(c, o); }
  if (lane == 0) { df[wid] = f; dc[wid] = c; }

  for (int cidx = wid; cidx < 4 * NB; cidx += 16) {
    float s = 0.f;
    for (int k = lane; k < NBLK2; k += 64) s += partial2[cidx * NBLK2 + k];
#pragma unroll
    for (int o = 32; o > 0; o >>= 1) s += __shfl_down(s, o);
    if (lane == 0) hist[cidx] = s;
  }
  __syncthreads();
  if (threadIdx.x == 0) {
    double ft = 0.0, ct = 0.0;
#pragma unroll
    for (int wv = 0; wv < 16; ++wv) { ft += df[wv]; ct += dc[wv]; }
    sh_f = (float)ft; sh_c = (float)ct;

    const float *hac = &hist[0], *hau = &hist[NB], *hic = &hist[2 * NB], *hiu = &hist[3 * NB];
    float tot_au = 0.f, tot_iu = 0.f;
    for (int s = 0; s < NB; ++s) { tot_au += hau[s]; tot_iu += hiu[s]; }
    float pac = 0.f, pau = 0.f, pic = 0.f, piu = 0.f, auc = 0.f, prev = 0.f;
    for (int t = 0; t < NTH; ++t) {
      pac += hac[t]; pau += hau[t]; pic += hic[t]; piu += hiu[t];
      float n_ac = pac, n_au = tot_au - pau, n_ic = pic, n_iu = tot_iu - piu;
      float avu = (n_ac + n_iu) / (n_ac + n_au + n_ic + n_iu + 1e-10f);
      if (t > 0) auc += 0.5f * (avu + prev) * 0.05f;
      prev = avu;
    }
    out[0] = -logf(auc + 1e-10f) + sh_f / (float)N;  // BETA = 1
    out[1] = sh_c / (float)N;
  }
}

extern "C" void kernel_launch(void* const* d_in, const int* in_sizes, int n_in,
                              void* d_out, int out_size, void* d_ws, size_t ws_size,
                              hipStream_t stream) {
  const float* probs = (const float*)d_in[0];
  const float* y     = (const float*)d_in[1];
  const float* w     = (const float*)d_in[2];
  float* out = (float*)d_out;
  int N = in_sizes[0] / C;

  Accum* acc = (Accum*)d_ws;
  size_t off_p2 = (sizeof(Accum) + 255) & ~(size_t)255;
  size_t off_st = (off_p2 + (size_t)(4 * NB) * NBLK2 * sizeof(float) + 255) & ~(size_t)255;
  size_t need   = off_st + (size_t)N * sizeof(float2);
  float*  partial2 = (float*)((char*)d_ws + off_p2);
  float2* stash    = (float2*)((char*)d_ws + off_st);

  if (ws_size >= need) {
    pass1_k<true><<<NBLK1, BS1, 0, stream>>>((const float4*)probs, (const float4*)y,
                                             (const float4*)w, y, acc, stash, N);
    pass2_k<<<NBLK2, BS2, 0, stream>>>(stash, acc, partial2, N);
  } else {
    pass1_k<false><<<NBLK1, BS1, 0, stream>>>((const float4*)probs, (const float4*)y,
                                              (const float4*)w, y, acc, nullptr, N);
    pass2f_k<<<NBLK2, BS2, 0, stream>>>((const float4*)probs, acc, partial2, N);
  }
  final_k<<<1, 1024, 0, stream>>>(partial2, acc, out, N);
}